// Round 6
// baseline (3533.564 us; speedup 1.0000x reference)
//
#include <hip/hip_runtime.h>
#include <cstdint>
#include <cstddef>

// VQ nearest-codebook, two-phase:
//   P1: fp16 MFMA approx scores -> per-row candidate set (superset, margin-sound).
//       R5/R6: codebook split 4-ways (grid 1024 = 4 blocks/CU demand; R4 root
//       cause was grid-limited occupancy at 2 blocks/CU) + CAND=16 so LDS
//       fits 3 blocks/CU. gload_lds width-16 staging + XOR swizzle kept.
//       (R5 bench died on container acquire; identical resubmit.)
//   P2: select (4-segment merge + singleton decide) -> dense pair worklist
//       -> packed u64 atomicMin argmin -> block-per-row fallback net -> gather.
constexpr int N_ROWS = 32768;
constexpr int KCODES = 8192;
constexpr int DIMS   = 512;
constexpr int NSEG   = 4;         // codebook quarters (one per block column)
constexpr int SEGC   = KCODES / NSEG;
constexpr int CAND   = 16;
constexpr float MARGIN = 1e-3f;   // approx err ~2e-4/side incl fp16 store slop
constexpr int PAIR_CAP = 1 << 18; // 256K pairs (post-filter expectation ~75K)
constexpr unsigned SENT = 0xFFFFFFFFu;

typedef _Float16 half8 __attribute__((ext_vector_type(8)));
typedef float    f32x4 __attribute__((ext_vector_type(4)));

// async global->LDS, 16B per lane; LDS dest is wave-uniform base + lane*16
__device__ __forceinline__ void gload16(const void* g, void* l) {
  __builtin_amdgcn_global_load_lds(
      (const __attribute__((address_space(1))) void*)g,
      (__attribute__((address_space(3))) void*)l, 16, 0, 0);
}

// packed candidate: high16 = fp16 bits of delta (= csq - 2*z.c approx),
// low16 = 13-bit global code id. Delta compares equal-offset per row (zsq).
__device__ __forceinline__ unsigned pack_ds(float d, int code) {
  union { _Float16 h; unsigned short u; } c; c.h = (_Float16)d;
  return ((unsigned)c.u << 16) | (unsigned)code;
}
__device__ __forceinline__ float unpack_d(unsigned e) {
  union { _Float16 h; unsigned short u; } c; c.u = (unsigned short)(e >> 16);
  return (float)c.h;
}

// ---- bitwise replica of np.sum(x*x,-1) fp32 pairwise (AVX512 npyv tree) ----
__global__ __launch_bounds__(256) void rowsq_kernel(const float* __restrict__ x,
                                                    float* __restrict__ out) {
  int row  = (blockIdx.x * 256 + threadIdx.x) >> 6;  // one row per wave
  int lane = threadIdx.x & 63;
  int blk = lane >> 4, l16 = lane & 15;
  const float* p = x + (size_t)row * DIMS + blk * 128 + l16;
  float A[8];
  #pragma unroll
  for (int j = 0; j < 8; ++j) { float v = p[16 * j]; A[j] = __fmul_rn(v, v); }
  float u = __fadd_rn(__fadd_rn(__fadd_rn(A[0], A[1]), __fadd_rn(A[2], A[3])),
                      __fadd_rn(__fadd_rn(A[4], A[5]), __fadd_rn(A[6], A[7])));
  u = __fadd_rn(u, __shfl_xor(u, 8, 64));
  u = __fadd_rn(u, __shfl_xor(u, 4, 64));
  u = __fadd_rn(u, __shfl_xor(u, 2, 64));
  u = __fadd_rn(u, __shfl_xor(u, 1, 64));
  u = __fadd_rn(u, __shfl_xor(u, 16, 64));
  u = __fadd_rn(u, __shfl_xor(u, 32, 64));
  if (lane == 0) out[row] = u;
}

// ---- fp32 -> fp16 converters (codebook scaled by 2^11, exact pow2) ----
__global__ __launch_bounds__(256) void cvt_cb_kernel(const float* __restrict__ cb,
                                                     _Float16* __restrict__ chs) {
  int i = blockIdx.x * 256 + threadIdx.x;          // 4 elements per thread
  float4 v = ((const float4*)cb)[i];
  union { _Float16 h[4]; uint2 u; } p;
  p.h[0] = (_Float16)(v.x * 2048.0f);
  p.h[1] = (_Float16)(v.y * 2048.0f);
  p.h[2] = (_Float16)(v.z * 2048.0f);
  p.h[3] = (_Float16)(v.w * 2048.0f);
  ((uint2*)chs)[i] = p.u;
}
__global__ __launch_bounds__(256) void cvt_z_kernel(const float* __restrict__ z,
                                                    _Float16* __restrict__ zh) {
  int i = blockIdx.x * 256 + threadIdx.x;
  float4 v = ((const float4*)z)[i];
  union { _Float16 h[4]; uint2 u; } p;
  p.h[0] = (_Float16)v.x; p.h[1] = (_Float16)v.y;
  p.h[2] = (_Float16)v.z; p.h[3] = (_Float16)v.w;
  ((uint2*)zh)[i] = p.u;
}

// ---- Phase 1: 128x128 MFMA tiles; gload_lds staging + XOR-swizzled LDS ----
// LDS tile: [row][64 halfs] = 128B/row, linear. Storage rule:
//   storage[row][c] = logical[row][c ^ ((row&7)<<4)]   (c = byte offset)
// gload_lds writes linearly (lane*16), so the SOURCE address carries the
// inverse swizzle; ds_read applies the same XOR.
template <bool ZH>
__global__ __launch_bounds__(256, 3) void vq_mfma_kernel(
    const float* __restrict__ z, const _Float16* __restrict__ zh,
    const _Float16* __restrict__ chs, const float* __restrict__ csq,
    unsigned* __restrict__ cand_g, int* __restrict__ cnt_g) {
  __shared__ __align__(16) _Float16 Ah[128 * 64];   // 16 KB
  __shared__ __align__(16) _Float16 Bh[128 * 64];   // 16 KB
  __shared__ unsigned rowmin_u[128];   // key = float_as_uint(delta + 4.0f) > 0
  __shared__ int cnt[128];
  __shared__ unsigned char dropped[128];
  __shared__ unsigned cand[128 * CAND];             // 8 KB

  const int tid  = threadIdx.x;
  const int seg  = blockIdx.x & (NSEG - 1);
  const int m0   = (blockIdx.x >> 2) * 128;
  const int nt0  = seg * SEGC;
  const int wave = tid >> 6, lane = tid & 63;
  const int wm = wave >> 1, wn = wave & 1;     // 2x2 wave grid of 64x64
  const int q = lane >> 4, r = lane & 15;

  // staging geometry: lane covers (row = base + lane/8, 16B slot = lane%8)
  const int lrow = lane >> 3;
  const int lcol = ((lane & 7) ^ lrow) << 4;   // inverse-swizzled byte-in-row
  const int s_r  = (r & 7) << 4;               // read-side XOR

  if (tid < 128) { rowmin_u[tid] = 0x7f800000u; cnt[tid] = 0; dropped[tid] = 0; }
  __syncthreads();

  for (int t = 0; t < SEGC / 128; ++t) {
    const int nt = nt0 + t * 128;
    f32x4 acc[4][4];
    #pragma unroll
    for (int mf = 0; mf < 4; ++mf)
      #pragma unroll
      for (int nf = 0; nf < 4; ++nf) acc[mf][nf] = (f32x4){0.f, 0.f, 0.f, 0.f};

    for (int kc = 0; kc < DIMS / 64; ++kc) {
      const int k0 = kc * 64;
      if (ZH) {  // async DMA: wave w stages rows [w*32, w*32+32) of A and B
        #pragma unroll
        for (int i = 0; i < 4; ++i) {
          const int rw = wave * 32 + i * 8;
          gload16((const char*)zh + ((size_t)(m0 + rw + lrow) * DIMS + k0) * 2 + lcol,
                  (char*)Ah + rw * 128);
          gload16((const char*)chs + ((size_t)(nt + rw + lrow) * DIMS + k0) * 2 + lcol,
                  (char*)Bh + rw * 128);
        }
      } else {   // convert-on-the-fly A (swizzled VGPR store); B via DMA
        #pragma unroll
        for (int i = 0; i < 4; ++i) {
          const int cc = i * 256 + tid;            // 1024 16B chunks
          const int rw = cc >> 3, cs = cc & 7;
          const float* src = z + (size_t)(m0 + rw) * DIMS + k0 + ((cs ^ (rw & 7)) << 3);
          float4 v0 = ((const float4*)src)[0], v1 = ((const float4*)src)[1];
          union { _Float16 h[8]; uint4 u; } p;
          p.h[0] = (_Float16)v0.x; p.h[1] = (_Float16)v0.y;
          p.h[2] = (_Float16)v0.z; p.h[3] = (_Float16)v0.w;
          p.h[4] = (_Float16)v1.x; p.h[5] = (_Float16)v1.y;
          p.h[6] = (_Float16)v1.z; p.h[7] = (_Float16)v1.w;
          *(uint4*)((char*)Ah + rw * 128 + cs * 16) = p.u;
        }
        #pragma unroll
        for (int i = 0; i < 4; ++i) {
          const int rw = wave * 32 + i * 8;
          gload16((const char*)chs + ((size_t)(nt + rw + lrow) * DIMS + k0) * 2 + lcol,
                  (char*)Bh + rw * 128);
        }
      }
      __syncthreads();   // drains vmcnt+lgkmcnt: tiles ready
      #pragma unroll
      for (int ks = 0; ks < 2; ++ks) {
        const int bb = ks * 64 + q * 16;
        half8 af[4], bf[4];
        #pragma unroll
        for (int mf = 0; mf < 4; ++mf)
          af[mf] = *(const half8*)((const char*)Ah +
                     (wm * 64 + mf * 16 + r) * 128 + (bb ^ s_r));
        #pragma unroll
        for (int nf = 0; nf < 4; ++nf)
          bf[nf] = *(const half8*)((const char*)Bh +
                     (wn * 64 + nf * 16 + r) * 128 + (bb ^ s_r));
        #pragma unroll
        for (int mf = 0; mf < 4; ++mf)
          #pragma unroll
          for (int nf = 0; nf < 4; ++nf)
            acc[mf][nf] = __builtin_amdgcn_mfma_f32_16x16x32_f16(
                af[mf], bf[nf], acc[mf][nf], 0, 0, 0);
      }
      __syncthreads();   // LDS consumed; next stage may overwrite
    }

    // ---- epilogue on delta = fl(csq - acc*2^-10)  (== sv - zsq, tiny mag,
    //      so fp32 rounding ~1e-8 and fp16 storage ~3e-5 -- margin-safe).
    //      C/D layout: row=q*4+reg, col=r.
    float cs[4];
    #pragma unroll
    for (int nf = 0; nf < 4; ++nf) cs[nf] = csq[nt + wn * 64 + nf * 16 + r];
    float m4[4][4];      // [mf][reg] lane-local min over nf
    #pragma unroll
    for (int mf = 0; mf < 4; ++mf)
      #pragma unroll
      for (int reg = 0; reg < 4; ++reg) {
        float mn = INFINITY;
        #pragma unroll
        for (int nf = 0; nf < 4; ++nf)
          mn = fminf(mn, __fmaf_rn(-0.0009765625f, acc[mf][nf][reg], cs[nf]));
        m4[mf][reg] = mn;
      }
    #pragma unroll
    for (int mf = 0; mf < 4; ++mf)
      #pragma unroll
      for (int reg = 0; reg < 4; ++reg) {
        float v = m4[mf][reg];
        v = fminf(v, __shfl_xor(v, 1, 64));
        v = fminf(v, __shfl_xor(v, 2, 64));
        v = fminf(v, __shfl_xor(v, 4, 64));
        v = fminf(v, __shfl_xor(v, 8, 64));
        m4[mf][reg] = v;
      }
    if (r == 0) {
      #pragma unroll
      for (int mf = 0; mf < 4; ++mf)
        #pragma unroll
        for (int reg = 0; reg < 4; ++reg)
          atomicMin(&rowmin_u[wm * 64 + mf * 16 + q * 4 + reg],
                    __float_as_uint(m4[mf][reg] + 4.0f));  // delta+4 > 0 always
    }
    // NO barrier here: rowmin only decreases, stale read = conservative
    // threshold = superset preserved; compaction removes the excess later.
    #pragma unroll
    for (int mf = 0; mf < 4; ++mf)
      #pragma unroll
      for (int reg = 0; reg < 4; ++reg) {
        const int row = wm * 64 + mf * 16 + q * 4 + reg;
        float thr = __uint_as_float(rowmin_u[row]) - 4.0f + MARGIN;
        #pragma unroll
        for (int nf = 0; nf < 4; ++nf) {
          float d = __fmaf_rn(-0.0009765625f, acc[mf][nf][reg], cs[nf]);
          if (d <= thr) {
            int slot = atomicAdd(&cnt[row], 1);
            if (slot < CAND)
              cand[row * CAND + slot] = pack_ds(d, nt + wn * 64 + nf * 16 + r);
          }
        }
      }
    // ---- periodic compaction: re-filter vs the tightened min so the raw
    //      counter never creeps past CAND; drop flag only on a real discard.
    if ((t & 3) == 3 || t == (SEGC / 128 - 1)) {
      __syncthreads();   // all appends for this tile visible
      if (tid < 128) {
        const int raw = cnt[tid];
        const int m = raw < CAND ? raw : CAND;
        if (raw > CAND) dropped[tid] = 1;
        const float thr = __uint_as_float(rowmin_u[tid]) - 4.0f + MARGIN;
        int k = 0;
        for (int i = 0; i < m; ++i) {
          unsigned e = cand[tid * CAND + i];
          if (unpack_d(e) <= thr) cand[tid * CAND + k++] = e;
        }
        cnt[tid] = k;
      }
      __syncthreads();
    }
  }
  __syncthreads();
  if (tid < 128)
    cnt_g[(size_t)seg * N_ROWS + m0 + tid] = dropped[tid] ? (CAND + 1) : cnt[tid];
  for (int i = tid; i < 128 * CAND; i += 256)
    cand_g[((size_t)seg * N_ROWS + m0 + i / CAND) * CAND + (i % CAND)] = cand[i];
}

// ---- exact bitwise-np score (R2-verified): dual-panel seq FMA chain ----
__device__ __forceinline__ float exact_q(const float* zr, const float* cr,
                                         float zsr, float csr) {
  float s1 = 0.f;
  for (int k = 0; k < 384; k += 8) {
    float4 a0 = *(const float4*)(zr + k), a1 = *(const float4*)(zr + k + 4);
    float4 b0 = *(const float4*)(cr + k), b1 = *(const float4*)(cr + k + 4);
    s1 = __fmaf_rn(a0.x, b0.x, s1); s1 = __fmaf_rn(a0.y, b0.y, s1);
    s1 = __fmaf_rn(a0.z, b0.z, s1); s1 = __fmaf_rn(a0.w, b0.w, s1);
    s1 = __fmaf_rn(a1.x, b1.x, s1); s1 = __fmaf_rn(a1.y, b1.y, s1);
    s1 = __fmaf_rn(a1.z, b1.z, s1); s1 = __fmaf_rn(a1.w, b1.w, s1);
  }
  float s2 = 0.f;
  for (int k = 384; k < 512; k += 8) {
    float4 a0 = *(const float4*)(zr + k), a1 = *(const float4*)(zr + k + 4);
    float4 b0 = *(const float4*)(cr + k), b1 = *(const float4*)(cr + k + 4);
    s2 = __fmaf_rn(a0.x, b0.x, s2); s2 = __fmaf_rn(a0.y, b0.y, s2);
    s2 = __fmaf_rn(a0.z, b0.z, s2); s2 = __fmaf_rn(a0.w, b0.w, s2);
    s2 = __fmaf_rn(a1.x, b1.x, s2); s2 = __fmaf_rn(a1.y, b1.y, s2);
    s2 = __fmaf_rn(a1.z, b1.z, s2); s2 = __fmaf_rn(a1.w, b1.w, s2);
  }
  float cross = __fadd_rn(s1, s2);                 // fl(S1 + S2)
  return __fadd_rn(__fmaf_rn(-2.f, cross, zsr), csr);
}

// ---- Phase 2a: 4-segment merge. Global approx-min filter; singleton rows
//      decided free (competitors provably > margin away); rest -> pair list.
__global__ __launch_bounds__(256) void select_kernel(
    const int* __restrict__ cnt_g, const unsigned* __restrict__ cand_g,
    unsigned long long* __restrict__ best, unsigned* __restrict__ pairs,
    int* __restrict__ meta, int* __restrict__ ovf) {
  const int row  = blockIdx.x * 256 + threadIdx.x;
  const int lane = threadIdx.x & 63;
  int c[NSEG]; bool over = false; int tot = 0;
  #pragma unroll
  for (int s = 0; s < NSEG; ++s) {
    c[s] = cnt_g[(size_t)s * N_ROWS + row];
    if (c[s] > CAND) over = true;
    tot += c[s];
  }
  if (tot == 0) over = true;
  unsigned long long bkey = ~0ULL;
  int need = 0;
  float thr = 0.f;
  if (!over) {
    float gm = INFINITY;
    #pragma unroll
    for (int s = 0; s < NSEG; ++s)
      for (int j = 0; j < c[s]; ++j)
        gm = fminf(gm, unpack_d(cand_g[((size_t)s * N_ROWS + row) * CAND + j]));
    thr = gm + MARGIN;
    int k = 0; unsigned first = 0;
    #pragma unroll
    for (int s = 0; s < NSEG; ++s)
      for (int j = 0; j < c[s]; ++j) {
        unsigned e = cand_g[((size_t)s * N_ROWS + row) * CAND + j];
        if (unpack_d(e) <= thr) { if (k == 0) first = e; ++k; }
      }
    if (k == 1) bkey = (unsigned long long)(first & 0x1FFFu);  // decided
    else need = k;
  }
  best[row] = bkey;
  // wave-aggregated worklist allocation (1 atomic per wave)
  int pre = need;
  #pragma unroll
  for (int off = 1; off < 64; off <<= 1) {
    int v = __shfl_up(pre, off, 64);
    if (lane >= off) pre += v;
  }
  int wtot = __shfl(pre, 63, 64);
  int base = 0;
  if (lane == 63 && wtot > 0) base = atomicAdd(&meta[0], wtot);
  base = __shfl(base, 63, 64);
  const int my0 = base + pre - need;              // exclusive prefix
  bool row_ovf = over;
  if (need > 0) {
    if (my0 + need > PAIR_CAP) {
      row_ovf = true;                             // fallback handles this row
      for (int j = 0; j < need; ++j) {            // sentinel allocated slots
        int s = my0 + j;
        if (s < PAIR_CAP) pairs[s] = SENT;
      }
    } else {
      int kk = 0;
      #pragma unroll
      for (int s = 0; s < NSEG; ++s)
        for (int j = 0; j < c[s]; ++j) {
          unsigned e = cand_g[((size_t)s * N_ROWS + row) * CAND + j];
          if (unpack_d(e) <= thr)
            pairs[my0 + kk++] = ((unsigned)row << 13) | (e & 0x1FFFu);
        }
    }
  }
  if (row_ovf) { int s = atomicAdd(&meta[1], 1); ovf[s] = row; }
}

// ---- Phase 2b: dense exact rescore, one lane per (row,code) pair.
//      d2 > 0 always (zsq ~ 512) so uint order == float order; packed key
//      (q_bits<<32)|code -> atomicMin = argmin with lowest-index tie-break.
__global__ __launch_bounds__(256) void pairs_kernel(
    const float* __restrict__ z, const float* __restrict__ cb,
    const float* __restrict__ zsq, const float* __restrict__ csq,
    const unsigned* __restrict__ pairs, const int* __restrict__ meta,
    unsigned long long* __restrict__ best) {
  int n = meta[0];
  if (n > PAIR_CAP) n = PAIR_CAP;
  const int i = blockIdx.x * 256 + threadIdx.x;
  if (i >= n) return;
  const unsigned p = pairs[i];
  if (p == SENT) return;                          // unfilled overflow slot
  const int row = (int)(p >> 13), code = (int)(p & 8191u);
  const float qv = exact_q(z + (size_t)row * DIMS, cb + (size_t)code * DIMS,
                           zsq[row], csq[code]);
  const unsigned long long key =
      ((unsigned long long)__float_as_uint(qv) << 32) | (unsigned)code;
  atomicMin(&best[row], key);
}

// ---- Phase 2c: overflow net, one BLOCK per row.
//      Pass A: coalesced approx scan (8-lane groups, fp32 tree dot), scores
//              to LDS, block min.  Pass B: exact_q within min + 5e-4.
__global__ __launch_bounds__(256) void fallback_kernel(
    const float* __restrict__ z, const float* __restrict__ cb,
    const float* __restrict__ zsq, const float* __restrict__ csq,
    const int* __restrict__ ovf, const int* __restrict__ meta,
    unsigned long long* __restrict__ best) {
  __shared__ float sc[KCODES];     // 32 KB approx deltas
  __shared__ float zrow[DIMS];     // 2 KB
  __shared__ unsigned bmin;
  const int n = meta[1];
  for (int wi = blockIdx.x; wi < n; wi += gridDim.x) {
    const int row = ovf[wi];
    for (int i = threadIdx.x; i < DIMS; i += 256)
      zrow[i] = z[(size_t)row * DIMS + i];
    if (threadIdx.x == 0) bmin = 0x7f800000u;
    __syncthreads();
    const int g = threadIdx.x >> 3;       // 32 groups of 8 lanes
    const int j = threadIdx.x & 7;
    float lmin = INFINITY;
    for (int c = g; c < KCODES; c += 32) {
      const float* cr = cb + (size_t)c * DIMS;
      float s = 0.f;
      #pragma unroll
      for (int i = 0; i < 16; ++i) {      // 64 dims per lane, 128B/group/step
        float4 a = *(const float4*)(&zrow[j * 4 + i * 32]);
        float4 b = *(const float4*)(cr + j * 4 + i * 32);
        s = __fmaf_rn(a.x, b.x, s); s = __fmaf_rn(a.y, b.y, s);
        s = __fmaf_rn(a.z, b.z, s); s = __fmaf_rn(a.w, b.w, s);
      }
      s += __shfl_xor(s, 1, 64);          // butterfly within 8-lane group
      s += __shfl_xor(s, 2, 64);
      s += __shfl_xor(s, 4, 64);
      float d = __fmaf_rn(-2.f, s, csq[c]);
      if (j == 0) sc[c] = d;
      lmin = fminf(lmin, d);
    }
    atomicMin(&bmin, __float_as_uint(lmin + 4.0f));   // delta+4 > 0
    __syncthreads();
    const float thr = __uint_as_float(bmin) - 4.0f + 5e-4f;
    const float zsr = zsq[row];
    const float* zr = z + (size_t)row * DIMS;
    for (int c = threadIdx.x; c < KCODES; c += 256) {
      if (sc[c] <= thr) {
        float qv = exact_q(zr, cb + (size_t)c * DIMS, zsr, csq[c]);
        unsigned long long key =
            ((unsigned long long)__float_as_uint(qv) << 32) | (unsigned)c;
        atomicMin(&best[row], key);
      }
    }
    __syncthreads();   // before next row reuses LDS
  }
}

// ---- Phase 2d: coalesced gather of winner rows + index write ----
__global__ __launch_bounds__(256) void gather_kernel(
    const float* __restrict__ cb, const unsigned long long* __restrict__ best,
    float* __restrict__ zq, float* __restrict__ idx_out) {
  const int wave = threadIdx.x >> 6, lane = threadIdx.x & 63;
  const int row = blockIdx.x * 4 + wave;
  const int code = (int)(unsigned)(best[row] & 0xFFFFFFFFu);
  if (lane == 0) idx_out[row] = (float)code;
  const float4* cbv = (const float4*)(cb + (size_t)code * DIMS);
  float4* zqv = (float4*)(zq + (size_t)row * DIMS);
  zqv[lane]      = cbv[lane];
  zqv[lane + 64] = cbv[lane + 64];
}

extern "C" void kernel_launch(void* const* d_in, const int* in_sizes, int n_in,
                              void* d_out, int out_size, void* d_ws, size_t ws_size,
                              hipStream_t stream) {
  const float* z  = (const float*)d_in[0];
  const float* cb = (const float*)d_in[1];
  float* out     = (float*)d_out;
  float* zq      = out;
  float* idx_out = out + (size_t)N_ROWS * DIMS;

  // workspace layout (all chunks 256B-multiples)
  char* w = (char*)d_ws;
  _Float16* cbh = (_Float16*)w;            w += (size_t)KCODES * DIMS * 2;   // 8 MB
  float* zsq = (float*)w;                  w += (size_t)N_ROWS * 4;          // 128 KB
  float* csq = (float*)w;                  w += (size_t)KCODES * 4;          // 32 KB
  int* cnt_g = (int*)w;                    w += (size_t)NSEG * N_ROWS * 4;   // 512 KB
  unsigned* cand_g = (unsigned*)w;         w += (size_t)NSEG * N_ROWS * CAND * 4; // 8MB
  unsigned long long* best = (unsigned long long*)w; w += (size_t)N_ROWS * 8;  // 256 KB
  unsigned* pairs = (unsigned*)w;          w += (size_t)PAIR_CAP * 4;        // 1 MB
  int* meta = (int*)w;                     w += 256;                         // counters
  int* ovf = (int*)w;                      w += (size_t)N_ROWS * 4;          // 128 KB
  _Float16* zh = (_Float16*)w;             w += (size_t)N_ROWS * DIMS * 2;   // 32 MB
  bool use_zh = ((size_t)(w - (char*)d_ws) <= ws_size);

  hipMemsetAsync(meta, 0, 256, stream);

  rowsq_kernel<<<N_ROWS / 4, 256, 0, stream>>>(z, zsq);
  rowsq_kernel<<<KCODES / 4, 256, 0, stream>>>(cb, csq);
  cvt_cb_kernel<<<KCODES * DIMS / 1024, 256, 0, stream>>>(cb, cbh);
  if (use_zh) {
    cvt_z_kernel<<<N_ROWS * DIMS / 1024, 256, 0, stream>>>(z, zh);
    vq_mfma_kernel<true><<<(N_ROWS / 128) * NSEG, 256, 0, stream>>>(
        z, zh, cbh, csq, cand_g, cnt_g);
  } else {
    vq_mfma_kernel<false><<<(N_ROWS / 128) * NSEG, 256, 0, stream>>>(
        z, nullptr, cbh, csq, cand_g, cnt_g);
  }
  select_kernel<<<N_ROWS / 256, 256, 0, stream>>>(cnt_g, cand_g, best, pairs,
                                                  meta, ovf);
  pairs_kernel<<<PAIR_CAP / 256, 256, 0, stream>>>(z, cb, zsq, csq, pairs,
                                                   meta, best);
  fallback_kernel<<<512, 256, 0, stream>>>(z, cb, zsq, csq, ovf, meta, best);
  gather_kernel<<<N_ROWS / 4, 256, 0, stream>>>(cb, best, zq, idx_out);
}

// Round 7
// 982.113 us; speedup vs baseline: 3.5979x; 3.5979x over previous
//
#include <hip/hip_runtime.h>
#include <cstdint>
#include <cstddef>

// VQ nearest-codebook, two-phase:
//   P1: fp16 MFMA approx scores -> per-row candidate set (superset, margin-sound).
//       R7: NSEG=4 kept (occupancy), CAND restored to 32 (R6's CAND=16 made
//       ~1000s of rows overflow -> 2.5ms fallback), post-atomicMin barrier
//       restored (tight thresholds), compaction every 2 tiles.
//       LDS = 49.2 KB -> still 3 blocks/CU.
//   P2: select (4-segment merge + singleton decide) -> dense pair worklist
//       -> packed u64 atomicMin argmin -> block-per-row fallback net -> gather.
constexpr int N_ROWS = 32768;
constexpr int KCODES = 8192;
constexpr int DIMS   = 512;
constexpr int NSEG   = 4;         // codebook quarters (one per block column)
constexpr int SEGC   = KCODES / NSEG;
constexpr int CAND   = 32;
constexpr float MARGIN = 1e-3f;   // approx err ~2e-4/side incl fp16 store slop
constexpr int PAIR_CAP = 1 << 18; // 256K pairs (post-filter expectation ~75K)
constexpr unsigned SENT = 0xFFFFFFFFu;

typedef _Float16 half8 __attribute__((ext_vector_type(8)));
typedef float    f32x4 __attribute__((ext_vector_type(4)));

// async global->LDS, 16B per lane; LDS dest is wave-uniform base + lane*16
__device__ __forceinline__ void gload16(const void* g, void* l) {
  __builtin_amdgcn_global_load_lds(
      (const __attribute__((address_space(1))) void*)g,
      (__attribute__((address_space(3))) void*)l, 16, 0, 0);
}

// packed candidate: high16 = fp16 bits of delta (= csq - 2*z.c approx),
// low16 = 13-bit global code id. Delta compares equal-offset per row (zsq).
__device__ __forceinline__ unsigned pack_ds(float d, int code) {
  union { _Float16 h; unsigned short u; } c; c.h = (_Float16)d;
  return ((unsigned)c.u << 16) | (unsigned)code;
}
__device__ __forceinline__ float unpack_d(unsigned e) {
  union { _Float16 h; unsigned short u; } c; c.u = (unsigned short)(e >> 16);
  return (float)c.h;
}

// ---- bitwise replica of np.sum(x*x,-1) fp32 pairwise (AVX512 npyv tree) ----
__global__ __launch_bounds__(256) void rowsq_kernel(const float* __restrict__ x,
                                                    float* __restrict__ out) {
  int row  = (blockIdx.x * 256 + threadIdx.x) >> 6;  // one row per wave
  int lane = threadIdx.x & 63;
  int blk = lane >> 4, l16 = lane & 15;
  const float* p = x + (size_t)row * DIMS + blk * 128 + l16;
  float A[8];
  #pragma unroll
  for (int j = 0; j < 8; ++j) { float v = p[16 * j]; A[j] = __fmul_rn(v, v); }
  float u = __fadd_rn(__fadd_rn(__fadd_rn(A[0], A[1]), __fadd_rn(A[2], A[3])),
                      __fadd_rn(__fadd_rn(A[4], A[5]), __fadd_rn(A[6], A[7])));
  u = __fadd_rn(u, __shfl_xor(u, 8, 64));
  u = __fadd_rn(u, __shfl_xor(u, 4, 64));
  u = __fadd_rn(u, __shfl_xor(u, 2, 64));
  u = __fadd_rn(u, __shfl_xor(u, 1, 64));
  u = __fadd_rn(u, __shfl_xor(u, 16, 64));
  u = __fadd_rn(u, __shfl_xor(u, 32, 64));
  if (lane == 0) out[row] = u;
}

// ---- fp32 -> fp16 converters (codebook scaled by 2^11, exact pow2) ----
__global__ __launch_bounds__(256) void cvt_cb_kernel(const float* __restrict__ cb,
                                                     _Float16* __restrict__ chs) {
  int i = blockIdx.x * 256 + threadIdx.x;          // 4 elements per thread
  float4 v = ((const float4*)cb)[i];
  union { _Float16 h[4]; uint2 u; } p;
  p.h[0] = (_Float16)(v.x * 2048.0f);
  p.h[1] = (_Float16)(v.y * 2048.0f);
  p.h[2] = (_Float16)(v.z * 2048.0f);
  p.h[3] = (_Float16)(v.w * 2048.0f);
  ((uint2*)chs)[i] = p.u;
}
__global__ __launch_bounds__(256) void cvt_z_kernel(const float* __restrict__ z,
                                                    _Float16* __restrict__ zh) {
  int i = blockIdx.x * 256 + threadIdx.x;
  float4 v = ((const float4*)z)[i];
  union { _Float16 h[4]; uint2 u; } p;
  p.h[0] = (_Float16)v.x; p.h[1] = (_Float16)v.y;
  p.h[2] = (_Float16)v.z; p.h[3] = (_Float16)v.w;
  ((uint2*)zh)[i] = p.u;
}

// ---- Phase 1: 128x128 MFMA tiles; gload_lds staging + XOR-swizzled LDS ----
// LDS tile: [row][64 halfs] = 128B/row, linear. Storage rule:
//   storage[row][c] = logical[row][c ^ ((row&7)<<4)]   (c = byte offset)
// gload_lds writes linearly (lane*16), so the SOURCE address carries the
// inverse swizzle; ds_read applies the same XOR.
template <bool ZH>
__global__ __launch_bounds__(256, 3) void vq_mfma_kernel(
    const float* __restrict__ z, const _Float16* __restrict__ zh,
    const _Float16* __restrict__ chs, const float* __restrict__ csq,
    unsigned* __restrict__ cand_g, int* __restrict__ cnt_g) {
  __shared__ __align__(16) _Float16 Ah[128 * 64];   // 16 KB
  __shared__ __align__(16) _Float16 Bh[128 * 64];   // 16 KB
  __shared__ unsigned rowmin_u[128];   // key = float_as_uint(delta + 4.0f) > 0
  __shared__ int cnt[128];
  __shared__ unsigned char dropped[128];
  __shared__ unsigned cand[128 * CAND];             // 16 KB

  const int tid  = threadIdx.x;
  const int seg  = blockIdx.x & (NSEG - 1);
  const int m0   = (blockIdx.x >> 2) * 128;
  const int nt0  = seg * SEGC;
  const int wave = tid >> 6, lane = tid & 63;
  const int wm = wave >> 1, wn = wave & 1;     // 2x2 wave grid of 64x64
  const int q = lane >> 4, r = lane & 15;

  // staging geometry: lane covers (row = base + lane/8, 16B slot = lane%8)
  const int lrow = lane >> 3;
  const int lcol = ((lane & 7) ^ lrow) << 4;   // inverse-swizzled byte-in-row
  const int s_r  = (r & 7) << 4;               // read-side XOR

  if (tid < 128) { rowmin_u[tid] = 0x7f800000u; cnt[tid] = 0; dropped[tid] = 0; }
  __syncthreads();

  for (int t = 0; t < SEGC / 128; ++t) {
    const int nt = nt0 + t * 128;
    f32x4 acc[4][4];
    #pragma unroll
    for (int mf = 0; mf < 4; ++mf)
      #pragma unroll
      for (int nf = 0; nf < 4; ++nf) acc[mf][nf] = (f32x4){0.f, 0.f, 0.f, 0.f};

    for (int kc = 0; kc < DIMS / 64; ++kc) {
      const int k0 = kc * 64;
      if (ZH) {  // async DMA: wave w stages rows [w*32, w*32+32) of A and B
        #pragma unroll
        for (int i = 0; i < 4; ++i) {
          const int rw = wave * 32 + i * 8;
          gload16((const char*)zh + ((size_t)(m0 + rw + lrow) * DIMS + k0) * 2 + lcol,
                  (char*)Ah + rw * 128);
          gload16((const char*)chs + ((size_t)(nt + rw + lrow) * DIMS + k0) * 2 + lcol,
                  (char*)Bh + rw * 128);
        }
      } else {   // convert-on-the-fly A (swizzled VGPR store); B via DMA
        #pragma unroll
        for (int i = 0; i < 4; ++i) {
          const int cc = i * 256 + tid;            // 1024 16B chunks
          const int rw = cc >> 3, cs = cc & 7;
          const float* src = z + (size_t)(m0 + rw) * DIMS + k0 + ((cs ^ (rw & 7)) << 3);
          float4 v0 = ((const float4*)src)[0], v1 = ((const float4*)src)[1];
          union { _Float16 h[8]; uint4 u; } p;
          p.h[0] = (_Float16)v0.x; p.h[1] = (_Float16)v0.y;
          p.h[2] = (_Float16)v0.z; p.h[3] = (_Float16)v0.w;
          p.h[4] = (_Float16)v1.x; p.h[5] = (_Float16)v1.y;
          p.h[6] = (_Float16)v1.z; p.h[7] = (_Float16)v1.w;
          *(uint4*)((char*)Ah + rw * 128 + cs * 16) = p.u;
        }
        #pragma unroll
        for (int i = 0; i < 4; ++i) {
          const int rw = wave * 32 + i * 8;
          gload16((const char*)chs + ((size_t)(nt + rw + lrow) * DIMS + k0) * 2 + lcol,
                  (char*)Bh + rw * 128);
        }
      }
      __syncthreads();   // drains vmcnt+lgkmcnt: tiles ready
      #pragma unroll
      for (int ks = 0; ks < 2; ++ks) {
        const int bb = ks * 64 + q * 16;
        half8 af[4], bf[4];
        #pragma unroll
        for (int mf = 0; mf < 4; ++mf)
          af[mf] = *(const half8*)((const char*)Ah +
                     (wm * 64 + mf * 16 + r) * 128 + (bb ^ s_r));
        #pragma unroll
        for (int nf = 0; nf < 4; ++nf)
          bf[nf] = *(const half8*)((const char*)Bh +
                     (wn * 64 + nf * 16 + r) * 128 + (bb ^ s_r));
        #pragma unroll
        for (int mf = 0; mf < 4; ++mf)
          #pragma unroll
          for (int nf = 0; nf < 4; ++nf)
            acc[mf][nf] = __builtin_amdgcn_mfma_f32_16x16x32_f16(
                af[mf], bf[nf], acc[mf][nf], 0, 0, 0);
      }
      __syncthreads();   // LDS consumed; next stage may overwrite
    }

    // ---- epilogue on delta = fl(csq - acc*2^-10)  (== sv - zsq, tiny mag,
    //      so fp32 rounding ~1e-8 and fp16 storage ~3e-5 -- margin-safe).
    //      C/D layout: row=q*4+reg, col=r.
    float cs[4];
    #pragma unroll
    for (int nf = 0; nf < 4; ++nf) cs[nf] = csq[nt + wn * 64 + nf * 16 + r];
    float m4[4][4];      // [mf][reg] lane-local min over nf
    #pragma unroll
    for (int mf = 0; mf < 4; ++mf)
      #pragma unroll
      for (int reg = 0; reg < 4; ++reg) {
        float mn = INFINITY;
        #pragma unroll
        for (int nf = 0; nf < 4; ++nf)
          mn = fminf(mn, __fmaf_rn(-0.0009765625f, acc[mf][nf][reg], cs[nf]));
        m4[mf][reg] = mn;
      }
    #pragma unroll
    for (int mf = 0; mf < 4; ++mf)
      #pragma unroll
      for (int reg = 0; reg < 4; ++reg) {
        float v = m4[mf][reg];
        v = fminf(v, __shfl_xor(v, 1, 64));
        v = fminf(v, __shfl_xor(v, 2, 64));
        v = fminf(v, __shfl_xor(v, 4, 64));
        v = fminf(v, __shfl_xor(v, 8, 64));
        m4[mf][reg] = v;
      }
    if (r == 0) {
      #pragma unroll
      for (int mf = 0; mf < 4; ++mf)
        #pragma unroll
        for (int reg = 0; reg < 4; ++reg)
          atomicMin(&rowmin_u[wm * 64 + mf * 16 + q * 4 + reg],
                    __float_as_uint(m4[mf][reg] + 4.0f));  // delta+4 > 0 always
    }
    __syncthreads();   // R7: tile-min includes BOTH waves before thresholding
    #pragma unroll
    for (int mf = 0; mf < 4; ++mf)
      #pragma unroll
      for (int reg = 0; reg < 4; ++reg) {
        const int row = wm * 64 + mf * 16 + q * 4 + reg;
        float thr = __uint_as_float(rowmin_u[row]) - 4.0f + MARGIN;
        #pragma unroll
        for (int nf = 0; nf < 4; ++nf) {
          float d = __fmaf_rn(-0.0009765625f, acc[mf][nf][reg], cs[nf]);
          if (d <= thr) {
            int slot = atomicAdd(&cnt[row], 1);
            if (slot < CAND)
              cand[row * CAND + slot] = pack_ds(d, nt + wn * 64 + nf * 16 + r);
          }
        }
      }
    // ---- periodic compaction: re-filter vs the tightened min so the raw
    //      counter never creeps past CAND; drop flag only on a real discard.
    //      Every 2 tiles (R7): compaction is ~32 LDS reads on 128 lanes.
    if ((t & 1) == 1 || t == (SEGC / 128 - 1)) {
      __syncthreads();   // all appends for this tile visible
      if (tid < 128) {
        const int raw = cnt[tid];
        const int m = raw < CAND ? raw : CAND;
        if (raw > CAND) dropped[tid] = 1;
        const float thr = __uint_as_float(rowmin_u[tid]) - 4.0f + MARGIN;
        int k = 0;
        for (int i = 0; i < m; ++i) {
          unsigned e = cand[tid * CAND + i];
          if (unpack_d(e) <= thr) cand[tid * CAND + k++] = e;
        }
        cnt[tid] = k;
      }
      __syncthreads();
    }
  }
  __syncthreads();
  if (tid < 128)
    cnt_g[(size_t)seg * N_ROWS + m0 + tid] = dropped[tid] ? (CAND + 1) : cnt[tid];
  for (int i = tid; i < 128 * CAND; i += 256)
    cand_g[((size_t)seg * N_ROWS + m0 + i / CAND) * CAND + (i % CAND)] = cand[i];
}

// ---- exact bitwise-np score (R2-verified): dual-panel seq FMA chain ----
__device__ __forceinline__ float exact_q(const float* zr, const float* cr,
                                         float zsr, float csr) {
  float s1 = 0.f;
  for (int k = 0; k < 384; k += 8) {
    float4 a0 = *(const float4*)(zr + k), a1 = *(const float4*)(zr + k + 4);
    float4 b0 = *(const float4*)(cr + k), b1 = *(const float4*)(cr + k + 4);
    s1 = __fmaf_rn(a0.x, b0.x, s1); s1 = __fmaf_rn(a0.y, b0.y, s1);
    s1 = __fmaf_rn(a0.z, b0.z, s1); s1 = __fmaf_rn(a0.w, b0.w, s1);
    s1 = __fmaf_rn(a1.x, b1.x, s1); s1 = __fmaf_rn(a1.y, b1.y, s1);
    s1 = __fmaf_rn(a1.z, b1.z, s1); s1 = __fmaf_rn(a1.w, b1.w, s1);
  }
  float s2 = 0.f;
  for (int k = 384; k < 512; k += 8) {
    float4 a0 = *(const float4*)(zr + k), a1 = *(const float4*)(zr + k + 4);
    float4 b0 = *(const float4*)(cr + k), b1 = *(const float4*)(cr + k + 4);
    s2 = __fmaf_rn(a0.x, b0.x, s2); s2 = __fmaf_rn(a0.y, b0.y, s2);
    s2 = __fmaf_rn(a0.z, b0.z, s2); s2 = __fmaf_rn(a0.w, b0.w, s2);
    s2 = __fmaf_rn(a1.x, b1.x, s2); s2 = __fmaf_rn(a1.y, b1.y, s2);
    s2 = __fmaf_rn(a1.z, b1.z, s2); s2 = __fmaf_rn(a1.w, b1.w, s2);
  }
  float cross = __fadd_rn(s1, s2);                 // fl(S1 + S2)
  return __fadd_rn(__fmaf_rn(-2.f, cross, zsr), csr);
}

// ---- Phase 2a: 4-segment merge. Global approx-min filter; singleton rows
//      decided free (competitors provably > margin away); rest -> pair list.
__global__ __launch_bounds__(256) void select_kernel(
    const int* __restrict__ cnt_g, const unsigned* __restrict__ cand_g,
    unsigned long long* __restrict__ best, unsigned* __restrict__ pairs,
    int* __restrict__ meta, int* __restrict__ ovf) {
  const int row  = blockIdx.x * 256 + threadIdx.x;
  const int lane = threadIdx.x & 63;
  int c[NSEG]; bool over = false; int tot = 0;
  #pragma unroll
  for (int s = 0; s < NSEG; ++s) {
    c[s] = cnt_g[(size_t)s * N_ROWS + row];
    if (c[s] > CAND) over = true;
    tot += c[s];
  }
  if (tot == 0) over = true;
  unsigned long long bkey = ~0ULL;
  int need = 0;
  float thr = 0.f;
  if (!over) {
    float gm = INFINITY;
    #pragma unroll
    for (int s = 0; s < NSEG; ++s)
      for (int j = 0; j < c[s]; ++j)
        gm = fminf(gm, unpack_d(cand_g[((size_t)s * N_ROWS + row) * CAND + j]));
    thr = gm + MARGIN;
    int k = 0; unsigned first = 0;
    #pragma unroll
    for (int s = 0; s < NSEG; ++s)
      for (int j = 0; j < c[s]; ++j) {
        unsigned e = cand_g[((size_t)s * N_ROWS + row) * CAND + j];
        if (unpack_d(e) <= thr) { if (k == 0) first = e; ++k; }
      }
    if (k == 1) bkey = (unsigned long long)(first & 0x1FFFu);  // decided
    else need = k;
  }
  best[row] = bkey;
  // wave-aggregated worklist allocation (1 atomic per wave)
  int pre = need;
  #pragma unroll
  for (int off = 1; off < 64; off <<= 1) {
    int v = __shfl_up(pre, off, 64);
    if (lane >= off) pre += v;
  }
  int wtot = __shfl(pre, 63, 64);
  int base = 0;
  if (lane == 63 && wtot > 0) base = atomicAdd(&meta[0], wtot);
  base = __shfl(base, 63, 64);
  const int my0 = base + pre - need;              // exclusive prefix
  bool row_ovf = over;
  if (need > 0) {
    if (my0 + need > PAIR_CAP) {
      row_ovf = true;                             // fallback handles this row
      for (int j = 0; j < need; ++j) {            // sentinel allocated slots
        int s = my0 + j;
        if (s < PAIR_CAP) pairs[s] = SENT;
      }
    } else {
      int kk = 0;
      #pragma unroll
      for (int s = 0; s < NSEG; ++s)
        for (int j = 0; j < c[s]; ++j) {
          unsigned e = cand_g[((size_t)s * N_ROWS + row) * CAND + j];
          if (unpack_d(e) <= thr)
            pairs[my0 + kk++] = ((unsigned)row << 13) | (e & 0x1FFFu);
        }
    }
  }
  if (row_ovf) { int s = atomicAdd(&meta[1], 1); ovf[s] = row; }
}

// ---- Phase 2b: dense exact rescore, one lane per (row,code) pair.
//      d2 > 0 always (zsq ~ 512) so uint order == float order; packed key
//      (q_bits<<32)|code -> atomicMin = argmin with lowest-index tie-break.
__global__ __launch_bounds__(256) void pairs_kernel(
    const float* __restrict__ z, const float* __restrict__ cb,
    const float* __restrict__ zsq, const float* __restrict__ csq,
    const unsigned* __restrict__ pairs, const int* __restrict__ meta,
    unsigned long long* __restrict__ best) {
  int n = meta[0];
  if (n > PAIR_CAP) n = PAIR_CAP;
  const int i = blockIdx.x * 256 + threadIdx.x;
  if (i >= n) return;
  const unsigned p = pairs[i];
  if (p == SENT) return;                          // unfilled overflow slot
  const int row = (int)(p >> 13), code = (int)(p & 8191u);
  const float qv = exact_q(z + (size_t)row * DIMS, cb + (size_t)code * DIMS,
                           zsq[row], csq[code]);
  const unsigned long long key =
      ((unsigned long long)__float_as_uint(qv) << 32) | (unsigned)code;
  atomicMin(&best[row], key);
}

// ---- Phase 2c: overflow net, one BLOCK per row.
//      Pass A: coalesced approx scan (8-lane groups, fp32 tree dot), scores
//              to LDS, block min.  Pass B: exact_q within min + 5e-4.
__global__ __launch_bounds__(256) void fallback_kernel(
    const float* __restrict__ z, const float* __restrict__ cb,
    const float* __restrict__ zsq, const float* __restrict__ csq,
    const int* __restrict__ ovf, const int* __restrict__ meta,
    unsigned long long* __restrict__ best) {
  __shared__ float sc[KCODES];     // 32 KB approx deltas
  __shared__ float zrow[DIMS];     // 2 KB
  __shared__ unsigned bmin;
  const int n = meta[1];
  for (int wi = blockIdx.x; wi < n; wi += gridDim.x) {
    const int row = ovf[wi];
    for (int i = threadIdx.x; i < DIMS; i += 256)
      zrow[i] = z[(size_t)row * DIMS + i];
    if (threadIdx.x == 0) bmin = 0x7f800000u;
    __syncthreads();
    const int g = threadIdx.x >> 3;       // 32 groups of 8 lanes
    const int j = threadIdx.x & 7;
    float lmin = INFINITY;
    for (int c = g; c < KCODES; c += 32) {
      const float* cr = cb + (size_t)c * DIMS;
      float s = 0.f;
      #pragma unroll
      for (int i = 0; i < 16; ++i) {      // 64 dims per lane, 128B/group/step
        float4 a = *(const float4*)(&zrow[j * 4 + i * 32]);
        float4 b = *(const float4*)(cr + j * 4 + i * 32);
        s = __fmaf_rn(a.x, b.x, s); s = __fmaf_rn(a.y, b.y, s);
        s = __fmaf_rn(a.z, b.z, s); s = __fmaf_rn(a.w, b.w, s);
      }
      s += __shfl_xor(s, 1, 64);          // butterfly within 8-lane group
      s += __shfl_xor(s, 2, 64);
      s += __shfl_xor(s, 4, 64);
      float d = __fmaf_rn(-2.f, s, csq[c]);
      if (j == 0) sc[c] = d;
      lmin = fminf(lmin, d);
    }
    atomicMin(&bmin, __float_as_uint(lmin + 4.0f));   // delta+4 > 0
    __syncthreads();
    const float thr = __uint_as_float(bmin) - 4.0f + 5e-4f;
    const float zsr = zsq[row];
    const float* zr = z + (size_t)row * DIMS;
    for (int c = threadIdx.x; c < KCODES; c += 256) {
      if (sc[c] <= thr) {
        float qv = exact_q(zr, cb + (size_t)c * DIMS, zsr, csq[c]);
        unsigned long long key =
            ((unsigned long long)__float_as_uint(qv) << 32) | (unsigned)c;
        atomicMin(&best[row], key);
      }
    }
    __syncthreads();   // before next row reuses LDS
  }
}

// ---- Phase 2d: coalesced gather of winner rows + index write ----
__global__ __launch_bounds__(256) void gather_kernel(
    const float* __restrict__ cb, const unsigned long long* __restrict__ best,
    float* __restrict__ zq, float* __restrict__ idx_out) {
  const int wave = threadIdx.x >> 6, lane = threadIdx.x & 63;
  const int row = blockIdx.x * 4 + wave;
  const int code = (int)(unsigned)(best[row] & 0xFFFFFFFFu);
  if (lane == 0) idx_out[row] = (float)code;
  const float4* cbv = (const float4*)(cb + (size_t)code * DIMS);
  float4* zqv = (float4*)(zq + (size_t)row * DIMS);
  zqv[lane]      = cbv[lane];
  zqv[lane + 64] = cbv[lane + 64];
}

extern "C" void kernel_launch(void* const* d_in, const int* in_sizes, int n_in,
                              void* d_out, int out_size, void* d_ws, size_t ws_size,
                              hipStream_t stream) {
  const float* z  = (const float*)d_in[0];
  const float* cb = (const float*)d_in[1];
  float* out     = (float*)d_out;
  float* zq      = out;
  float* idx_out = out + (size_t)N_ROWS * DIMS;

  // workspace layout (all chunks 256B-multiples)
  char* w = (char*)d_ws;
  _Float16* cbh = (_Float16*)w;            w += (size_t)KCODES * DIMS * 2;   // 8 MB
  float* zsq = (float*)w;                  w += (size_t)N_ROWS * 4;          // 128 KB
  float* csq = (float*)w;                  w += (size_t)KCODES * 4;          // 32 KB
  int* cnt_g = (int*)w;                    w += (size_t)NSEG * N_ROWS * 4;   // 512 KB
  unsigned* cand_g = (unsigned*)w;         w += (size_t)NSEG * N_ROWS * CAND * 4; // 16MB
  unsigned long long* best = (unsigned long long*)w; w += (size_t)N_ROWS * 8;  // 256 KB
  unsigned* pairs = (unsigned*)w;          w += (size_t)PAIR_CAP * 4;        // 1 MB
  int* meta = (int*)w;                     w += 256;                         // counters
  int* ovf = (int*)w;                      w += (size_t)N_ROWS * 4;          // 128 KB
  _Float16* zh = (_Float16*)w;             w += (size_t)N_ROWS * DIMS * 2;   // 32 MB
  bool use_zh = ((size_t)(w - (char*)d_ws) <= ws_size);

  hipMemsetAsync(meta, 0, 256, stream);

  rowsq_kernel<<<N_ROWS / 4, 256, 0, stream>>>(z, zsq);
  rowsq_kernel<<<KCODES / 4, 256, 0, stream>>>(cb, csq);
  cvt_cb_kernel<<<KCODES * DIMS / 1024, 256, 0, stream>>>(cb, cbh);
  if (use_zh) {
    cvt_z_kernel<<<N_ROWS * DIMS / 1024, 256, 0, stream>>>(z, zh);
    vq_mfma_kernel<true><<<(N_ROWS / 128) * NSEG, 256, 0, stream>>>(
        z, zh, cbh, csq, cand_g, cnt_g);
  } else {
    vq_mfma_kernel<false><<<(N_ROWS / 128) * NSEG, 256, 0, stream>>>(
        z, nullptr, cbh, csq, cand_g, cnt_g);
  }
  select_kernel<<<N_ROWS / 256, 256, 0, stream>>>(cnt_g, cand_g, best, pairs,
                                                  meta, ovf);
  pairs_kernel<<<PAIR_CAP / 256, 256, 0, stream>>>(z, cb, zsq, csq, pairs,
                                                   meta, best);
  fallback_kernel<<<512, 256, 0, stream>>>(z, cb, zsq, csq, ovf, meta, best);
  gather_kernel<<<N_ROWS / 4, 256, 0, stream>>>(cb, best, zq, idx_out);
}

// Round 8
// 745.462 us; speedup vs baseline: 4.7401x; 1.3175x over previous
//
#include <hip/hip_runtime.h>
#include <cstdint>
#include <cstddef>

// VQ nearest-codebook, two-phase:
//   P1: fp16 MFMA approx scores -> per-row candidate set (superset, margin-sound).
//       R8: 512-thread blocks, 8 waves in 2x4 grid, 64x32 per wave ->
//       acc = 32 AGPRs (was 64). R4/R7 occupancy was register-capped:
//       84 VGPR + 64 AGPR = 148 > 128 -> 8 waves/CU (m69 halving rule).
//       Now ~102 total -> 16 waves/CU. Tile/LDS/staging unchanged.
//   P2: select (4-segment merge + singleton decide) -> dense pair worklist
//       -> packed u64 atomicMin argmin -> block-per-row fallback net -> gather.
constexpr int N_ROWS = 32768;
constexpr int KCODES = 8192;
constexpr int DIMS   = 512;
constexpr int NSEG   = 4;         // codebook quarters (one per block column)
constexpr int SEGC   = KCODES / NSEG;
constexpr int CAND   = 32;
constexpr float MARGIN = 1e-3f;   // approx err ~2e-4/side incl fp16 store slop
constexpr int PAIR_CAP = 1 << 18; // 256K pairs (post-filter expectation ~75K)
constexpr unsigned SENT = 0xFFFFFFFFu;

typedef _Float16 half8 __attribute__((ext_vector_type(8)));
typedef float    f32x4 __attribute__((ext_vector_type(4)));

// async global->LDS, 16B per lane; LDS dest is wave-uniform base + lane*16
__device__ __forceinline__ void gload16(const void* g, void* l) {
  __builtin_amdgcn_global_load_lds(
      (const __attribute__((address_space(1))) void*)g,
      (__attribute__((address_space(3))) void*)l, 16, 0, 0);
}

// packed candidate: high16 = fp16 bits of delta (= csq - 2*z.c approx),
// low16 = 13-bit global code id. Delta compares equal-offset per row (zsq).
__device__ __forceinline__ unsigned pack_ds(float d, int code) {
  union { _Float16 h; unsigned short u; } c; c.h = (_Float16)d;
  return ((unsigned)c.u << 16) | (unsigned)code;
}
__device__ __forceinline__ float unpack_d(unsigned e) {
  union { _Float16 h; unsigned short u; } c; c.u = (unsigned short)(e >> 16);
  return (float)c.h;
}

// ---- bitwise replica of np.sum(x*x,-1) fp32 pairwise (AVX512 npyv tree) ----
__global__ __launch_bounds__(256) void rowsq_kernel(const float* __restrict__ x,
                                                    float* __restrict__ out) {
  int row  = (blockIdx.x * 256 + threadIdx.x) >> 6;  // one row per wave
  int lane = threadIdx.x & 63;
  int blk = lane >> 4, l16 = lane & 15;
  const float* p = x + (size_t)row * DIMS + blk * 128 + l16;
  float A[8];
  #pragma unroll
  for (int j = 0; j < 8; ++j) { float v = p[16 * j]; A[j] = __fmul_rn(v, v); }
  float u = __fadd_rn(__fadd_rn(__fadd_rn(A[0], A[1]), __fadd_rn(A[2], A[3])),
                      __fadd_rn(__fadd_rn(A[4], A[5]), __fadd_rn(A[6], A[7])));
  u = __fadd_rn(u, __shfl_xor(u, 8, 64));
  u = __fadd_rn(u, __shfl_xor(u, 4, 64));
  u = __fadd_rn(u, __shfl_xor(u, 2, 64));
  u = __fadd_rn(u, __shfl_xor(u, 1, 64));
  u = __fadd_rn(u, __shfl_xor(u, 16, 64));
  u = __fadd_rn(u, __shfl_xor(u, 32, 64));
  if (lane == 0) out[row] = u;
}

// ---- fp32 -> fp16 converters (codebook scaled by 2^11, exact pow2) ----
__global__ __launch_bounds__(256) void cvt_cb_kernel(const float* __restrict__ cb,
                                                     _Float16* __restrict__ chs) {
  int i = blockIdx.x * 256 + threadIdx.x;          // 4 elements per thread
  float4 v = ((const float4*)cb)[i];
  union { _Float16 h[4]; uint2 u; } p;
  p.h[0] = (_Float16)(v.x * 2048.0f);
  p.h[1] = (_Float16)(v.y * 2048.0f);
  p.h[2] = (_Float16)(v.z * 2048.0f);
  p.h[3] = (_Float16)(v.w * 2048.0f);
  ((uint2*)chs)[i] = p.u;
}
__global__ __launch_bounds__(256) void cvt_z_kernel(const float* __restrict__ z,
                                                    _Float16* __restrict__ zh) {
  int i = blockIdx.x * 256 + threadIdx.x;
  float4 v = ((const float4*)z)[i];
  union { _Float16 h[4]; uint2 u; } p;
  p.h[0] = (_Float16)v.x; p.h[1] = (_Float16)v.y;
  p.h[2] = (_Float16)v.z; p.h[3] = (_Float16)v.w;
  ((uint2*)zh)[i] = p.u;
}

// ---- Phase 1: 128x128 MFMA tiles; gload_lds staging + XOR-swizzled LDS ----
// LDS tile: [row][64 halfs] = 128B/row, linear. Storage rule:
//   storage[row][c] = logical[row][c ^ ((row&7)<<4)]   (c = byte offset)
// gload_lds writes linearly (lane*16), so the SOURCE address carries the
// inverse swizzle; ds_read applies the same XOR.
// 8 waves, 2x4 grid: wave (wm,wn) owns rows [wm*64,+64) x cols [wn*32,+32).
template <bool ZH>
__global__ __launch_bounds__(512, 4) void vq_mfma_kernel(
    const float* __restrict__ z, const _Float16* __restrict__ zh,
    const _Float16* __restrict__ chs, const float* __restrict__ csq,
    unsigned* __restrict__ cand_g, int* __restrict__ cnt_g) {
  __shared__ __align__(16) _Float16 Ah[128 * 64];   // 16 KB
  __shared__ __align__(16) _Float16 Bh[128 * 64];   // 16 KB
  __shared__ unsigned rowmin_u[128];   // key = float_as_uint(delta + 4.0f) > 0
  __shared__ int cnt[128];
  __shared__ unsigned char dropped[128];
  __shared__ unsigned cand[128 * CAND];             // 16 KB

  const int tid  = threadIdx.x;
  const int seg  = blockIdx.x & (NSEG - 1);
  const int m0   = (blockIdx.x >> 2) * 128;
  const int nt0  = seg * SEGC;
  const int wave = tid >> 6, lane = tid & 63;
  const int wm = wave >> 2, wn = wave & 3;     // 2x4 wave grid of 64x32
  const int q = lane >> 4, r = lane & 15;

  // staging geometry: lane covers (row = base + lane/8, 16B slot = lane%8)
  const int lrow = lane >> 3;
  const int lcol = ((lane & 7) ^ lrow) << 4;   // inverse-swizzled byte-in-row
  const int s_r  = (r & 7) << 4;               // read-side XOR

  if (tid < 128) { rowmin_u[tid] = 0x7f800000u; cnt[tid] = 0; dropped[tid] = 0; }
  __syncthreads();

  for (int t = 0; t < SEGC / 128; ++t) {
    const int nt = nt0 + t * 128;
    f32x4 acc[4][2];
    #pragma unroll
    for (int mf = 0; mf < 4; ++mf)
      #pragma unroll
      for (int nf = 0; nf < 2; ++nf) acc[mf][nf] = (f32x4){0.f, 0.f, 0.f, 0.f};

    for (int kc = 0; kc < DIMS / 64; ++kc) {
      const int k0 = kc * 64;
      if (ZH) {  // async DMA: wave w stages rows [w*16, w*16+16) of A and B
        #pragma unroll
        for (int i = 0; i < 2; ++i) {
          const int rw = wave * 16 + i * 8;
          gload16((const char*)zh + ((size_t)(m0 + rw + lrow) * DIMS + k0) * 2 + lcol,
                  (char*)Ah + rw * 128);
          gload16((const char*)chs + ((size_t)(nt + rw + lrow) * DIMS + k0) * 2 + lcol,
                  (char*)Bh + rw * 128);
        }
      } else {   // convert-on-the-fly A (swizzled VGPR store); B via DMA
        #pragma unroll
        for (int i = 0; i < 2; ++i) {
          const int cc = i * 512 + tid;            // 1024 16B chunks
          const int rw = cc >> 3, cs = cc & 7;
          const float* src = z + (size_t)(m0 + rw) * DIMS + k0 + ((cs ^ (rw & 7)) << 3);
          float4 v0 = ((const float4*)src)[0], v1 = ((const float4*)src)[1];
          union { _Float16 h[8]; uint4 u; } p;
          p.h[0] = (_Float16)v0.x; p.h[1] = (_Float16)v0.y;
          p.h[2] = (_Float16)v0.z; p.h[3] = (_Float16)v0.w;
          p.h[4] = (_Float16)v1.x; p.h[5] = (_Float16)v1.y;
          p.h[6] = (_Float16)v1.z; p.h[7] = (_Float16)v1.w;
          *(uint4*)((char*)Ah + rw * 128 + cs * 16) = p.u;
        }
        #pragma unroll
        for (int i = 0; i < 2; ++i) {
          const int rw = wave * 16 + i * 8;
          gload16((const char*)chs + ((size_t)(nt + rw + lrow) * DIMS + k0) * 2 + lcol,
                  (char*)Bh + rw * 128);
        }
      }
      __syncthreads();   // drains vmcnt+lgkmcnt: tiles ready
      #pragma unroll
      for (int ks = 0; ks < 2; ++ks) {
        const int bb = ks * 64 + q * 16;
        half8 af[4], bf[2];
        #pragma unroll
        for (int mf = 0; mf < 4; ++mf)
          af[mf] = *(const half8*)((const char*)Ah +
                     (wm * 64 + mf * 16 + r) * 128 + (bb ^ s_r));
        #pragma unroll
        for (int nf = 0; nf < 2; ++nf)
          bf[nf] = *(const half8*)((const char*)Bh +
                     (wn * 32 + nf * 16 + r) * 128 + (bb ^ s_r));
        #pragma unroll
        for (int mf = 0; mf < 4; ++mf)
          #pragma unroll
          for (int nf = 0; nf < 2; ++nf)
            acc[mf][nf] = __builtin_amdgcn_mfma_f32_16x16x32_f16(
                af[mf], bf[nf], acc[mf][nf], 0, 0, 0);
      }
      __syncthreads();   // LDS consumed; next stage may overwrite
    }

    // ---- epilogue on delta = fl(csq - acc*2^-10)  (== sv - zsq, tiny mag,
    //      so fp32 rounding ~1e-8 and fp16 storage ~3e-5 -- margin-safe).
    //      C/D layout: row=q*4+reg, col=r.
    float cs[2];
    #pragma unroll
    for (int nf = 0; nf < 2; ++nf) cs[nf] = csq[nt + wn * 32 + nf * 16 + r];
    float m4[4][4];      // [mf][reg] lane-local min over nf
    #pragma unroll
    for (int mf = 0; mf < 4; ++mf)
      #pragma unroll
      for (int reg = 0; reg < 4; ++reg) {
        float mn = INFINITY;
        #pragma unroll
        for (int nf = 0; nf < 2; ++nf)
          mn = fminf(mn, __fmaf_rn(-0.0009765625f, acc[mf][nf][reg], cs[nf]));
        m4[mf][reg] = mn;
      }
    #pragma unroll
    for (int mf = 0; mf < 4; ++mf)
      #pragma unroll
      for (int reg = 0; reg < 4; ++reg) {
        float v = m4[mf][reg];
        v = fminf(v, __shfl_xor(v, 1, 64));
        v = fminf(v, __shfl_xor(v, 2, 64));
        v = fminf(v, __shfl_xor(v, 4, 64));
        v = fminf(v, __shfl_xor(v, 8, 64));
        m4[mf][reg] = v;
      }
    if (r == 0) {
      #pragma unroll
      for (int mf = 0; mf < 4; ++mf)
        #pragma unroll
        for (int reg = 0; reg < 4; ++reg)
          atomicMin(&rowmin_u[wm * 64 + mf * 16 + q * 4 + reg],
                    __float_as_uint(m4[mf][reg] + 4.0f));  // delta+4 > 0 always
    }
    __syncthreads();   // tile-min includes ALL waves before thresholding
    #pragma unroll
    for (int mf = 0; mf < 4; ++mf)
      #pragma unroll
      for (int reg = 0; reg < 4; ++reg) {
        const int row = wm * 64 + mf * 16 + q * 4 + reg;
        float thr = __uint_as_float(rowmin_u[row]) - 4.0f + MARGIN;
        #pragma unroll
        for (int nf = 0; nf < 2; ++nf) {
          float d = __fmaf_rn(-0.0009765625f, acc[mf][nf][reg], cs[nf]);
          if (d <= thr) {
            int slot = atomicAdd(&cnt[row], 1);
            if (slot < CAND)
              cand[row * CAND + slot] = pack_ds(d, nt + wn * 32 + nf * 16 + r);
          }
        }
      }
    // ---- periodic compaction: re-filter vs the tightened min so the raw
    //      counter never creeps past CAND; drop flag only on a real discard.
    if ((t & 1) == 1 || t == (SEGC / 128 - 1)) {
      __syncthreads();   // all appends for this tile visible
      if (tid < 128) {
        const int raw = cnt[tid];
        const int m = raw < CAND ? raw : CAND;
        if (raw > CAND) dropped[tid] = 1;
        const float thr = __uint_as_float(rowmin_u[tid]) - 4.0f + MARGIN;
        int k = 0;
        for (int i = 0; i < m; ++i) {
          unsigned e = cand[tid * CAND + i];
          if (unpack_d(e) <= thr) cand[tid * CAND + k++] = e;
        }
        cnt[tid] = k;
      }
      __syncthreads();
    }
  }
  __syncthreads();
  if (tid < 128)
    cnt_g[(size_t)seg * N_ROWS + m0 + tid] = dropped[tid] ? (CAND + 1) : cnt[tid];
  for (int i = tid; i < 128 * CAND; i += 512)
    cand_g[((size_t)seg * N_ROWS + m0 + i / CAND) * CAND + (i % CAND)] = cand[i];
}

// ---- exact bitwise-np score (R2-verified): dual-panel seq FMA chain ----
__device__ __forceinline__ float exact_q(const float* zr, const float* cr,
                                         float zsr, float csr) {
  float s1 = 0.f;
  for (int k = 0; k < 384; k += 8) {
    float4 a0 = *(const float4*)(zr + k), a1 = *(const float4*)(zr + k + 4);
    float4 b0 = *(const float4*)(cr + k), b1 = *(const float4*)(cr + k + 4);
    s1 = __fmaf_rn(a0.x, b0.x, s1); s1 = __fmaf_rn(a0.y, b0.y, s1);
    s1 = __fmaf_rn(a0.z, b0.z, s1); s1 = __fmaf_rn(a0.w, b0.w, s1);
    s1 = __fmaf_rn(a1.x, b1.x, s1); s1 = __fmaf_rn(a1.y, b1.y, s1);
    s1 = __fmaf_rn(a1.z, b1.z, s1); s1 = __fmaf_rn(a1.w, b1.w, s1);
  }
  float s2 = 0.f;
  for (int k = 384; k < 512; k += 8) {
    float4 a0 = *(const float4*)(zr + k), a1 = *(const float4*)(zr + k + 4);
    float4 b0 = *(const float4*)(cr + k), b1 = *(const float4*)(cr + k + 4);
    s2 = __fmaf_rn(a0.x, b0.x, s2); s2 = __fmaf_rn(a0.y, b0.y, s2);
    s2 = __fmaf_rn(a0.z, b0.z, s2); s2 = __fmaf_rn(a0.w, b0.w, s2);
    s2 = __fmaf_rn(a1.x, b1.x, s2); s2 = __fmaf_rn(a1.y, b1.y, s2);
    s2 = __fmaf_rn(a1.z, b1.z, s2); s2 = __fmaf_rn(a1.w, b1.w, s2);
  }
  float cross = __fadd_rn(s1, s2);                 // fl(S1 + S2)
  return __fadd_rn(__fmaf_rn(-2.f, cross, zsr), csr);
}

// ---- Phase 2a: 4-segment merge. Global approx-min filter; singleton rows
//      decided free (competitors provably > margin away); rest -> pair list.
__global__ __launch_bounds__(256) void select_kernel(
    const int* __restrict__ cnt_g, const unsigned* __restrict__ cand_g,
    unsigned long long* __restrict__ best, unsigned* __restrict__ pairs,
    int* __restrict__ meta, int* __restrict__ ovf) {
  const int row  = blockIdx.x * 256 + threadIdx.x;
  const int lane = threadIdx.x & 63;
  int c[NSEG]; bool over = false; int tot = 0;
  #pragma unroll
  for (int s = 0; s < NSEG; ++s) {
    c[s] = cnt_g[(size_t)s * N_ROWS + row];
    if (c[s] > CAND) over = true;
    tot += c[s];
  }
  if (tot == 0) over = true;
  unsigned long long bkey = ~0ULL;
  int need = 0;
  float thr = 0.f;
  if (!over) {
    float gm = INFINITY;
    #pragma unroll
    for (int s = 0; s < NSEG; ++s)
      for (int j = 0; j < c[s]; ++j)
        gm = fminf(gm, unpack_d(cand_g[((size_t)s * N_ROWS + row) * CAND + j]));
    thr = gm + MARGIN;
    int k = 0; unsigned first = 0;
    #pragma unroll
    for (int s = 0; s < NSEG; ++s)
      for (int j = 0; j < c[s]; ++j) {
        unsigned e = cand_g[((size_t)s * N_ROWS + row) * CAND + j];
        if (unpack_d(e) <= thr) { if (k == 0) first = e; ++k; }
      }
    if (k == 1) bkey = (unsigned long long)(first & 0x1FFFu);  // decided
    else need = k;
  }
  best[row] = bkey;
  // wave-aggregated worklist allocation (1 atomic per wave)
  int pre = need;
  #pragma unroll
  for (int off = 1; off < 64; off <<= 1) {
    int v = __shfl_up(pre, off, 64);
    if (lane >= off) pre += v;
  }
  int wtot = __shfl(pre, 63, 64);
  int base = 0;
  if (lane == 63 && wtot > 0) base = atomicAdd(&meta[0], wtot);
  base = __shfl(base, 63, 64);
  const int my0 = base + pre - need;              // exclusive prefix
  bool row_ovf = over;
  if (need > 0) {
    if (my0 + need > PAIR_CAP) {
      row_ovf = true;                             // fallback handles this row
      for (int j = 0; j < need; ++j) {            // sentinel allocated slots
        int s = my0 + j;
        if (s < PAIR_CAP) pairs[s] = SENT;
      }
    } else {
      int kk = 0;
      #pragma unroll
      for (int s = 0; s < NSEG; ++s)
        for (int j = 0; j < c[s]; ++j) {
          unsigned e = cand_g[((size_t)s * N_ROWS + row) * CAND + j];
          if (unpack_d(e) <= thr)
            pairs[my0 + kk++] = ((unsigned)row << 13) | (e & 0x1FFFu);
        }
    }
  }
  if (row_ovf) { int s = atomicAdd(&meta[1], 1); ovf[s] = row; }
}

// ---- Phase 2b: dense exact rescore, one lane per (row,code) pair.
//      d2 > 0 always (zsq ~ 512) so uint order == float order; packed key
//      (q_bits<<32)|code -> atomicMin = argmin with lowest-index tie-break.
__global__ __launch_bounds__(256) void pairs_kernel(
    const float* __restrict__ z, const float* __restrict__ cb,
    const float* __restrict__ zsq, const float* __restrict__ csq,
    const unsigned* __restrict__ pairs, const int* __restrict__ meta,
    unsigned long long* __restrict__ best) {
  int n = meta[0];
  if (n > PAIR_CAP) n = PAIR_CAP;
  const int i = blockIdx.x * 256 + threadIdx.x;
  if (i >= n) return;
  const unsigned p = pairs[i];
  if (p == SENT) return;                          // unfilled overflow slot
  const int row = (int)(p >> 13), code = (int)(p & 8191u);
  const float qv = exact_q(z + (size_t)row * DIMS, cb + (size_t)code * DIMS,
                           zsq[row], csq[code]);
  const unsigned long long key =
      ((unsigned long long)__float_as_uint(qv) << 32) | (unsigned)code;
  atomicMin(&best[row], key);
}

// ---- Phase 2c: overflow net, one BLOCK per row.
//      Pass A: coalesced approx scan (8-lane groups, fp32 tree dot), scores
//              to LDS, block min.  Pass B: exact_q within min + 5e-4.
__global__ __launch_bounds__(256) void fallback_kernel(
    const float* __restrict__ z, const float* __restrict__ cb,
    const float* __restrict__ zsq, const float* __restrict__ csq,
    const int* __restrict__ ovf, const int* __restrict__ meta,
    unsigned long long* __restrict__ best) {
  __shared__ float sc[KCODES];     // 32 KB approx deltas
  __shared__ float zrow[DIMS];     // 2 KB
  __shared__ unsigned bmin;
  const int n = meta[1];
  for (int wi = blockIdx.x; wi < n; wi += gridDim.x) {
    const int row = ovf[wi];
    for (int i = threadIdx.x; i < DIMS; i += 256)
      zrow[i] = z[(size_t)row * DIMS + i];
    if (threadIdx.x == 0) bmin = 0x7f800000u;
    __syncthreads();
    const int g = threadIdx.x >> 3;       // 32 groups of 8 lanes
    const int j = threadIdx.x & 7;
    float lmin = INFINITY;
    for (int c = g; c < KCODES; c += 32) {
      const float* cr = cb + (size_t)c * DIMS;
      float s = 0.f;
      #pragma unroll
      for (int i = 0; i < 16; ++i) {      // 64 dims per lane, 128B/group/step
        float4 a = *(const float4*)(&zrow[j * 4 + i * 32]);
        float4 b = *(const float4*)(cr + j * 4 + i * 32);
        s = __fmaf_rn(a.x, b.x, s); s = __fmaf_rn(a.y, b.y, s);
        s = __fmaf_rn(a.z, b.z, s); s = __fmaf_rn(a.w, b.w, s);
      }
      s += __shfl_xor(s, 1, 64);          // butterfly within 8-lane group
      s += __shfl_xor(s, 2, 64);
      s += __shfl_xor(s, 4, 64);
      float d = __fmaf_rn(-2.f, s, csq[c]);
      if (j == 0) sc[c] = d;
      lmin = fminf(lmin, d);
    }
    atomicMin(&bmin, __float_as_uint(lmin + 4.0f));   // delta+4 > 0
    __syncthreads();
    const float thr = __uint_as_float(bmin) - 4.0f + 5e-4f;
    const float zsr = zsq[row];
    const float* zr = z + (size_t)row * DIMS;
    for (int c = threadIdx.x; c < KCODES; c += 256) {
      if (sc[c] <= thr) {
        float qv = exact_q(zr, cb + (size_t)c * DIMS, zsr, csq[c]);
        unsigned long long key =
            ((unsigned long long)__float_as_uint(qv) << 32) | (unsigned)c;
        atomicMin(&best[row], key);
      }
    }
    __syncthreads();   // before next row reuses LDS
  }
}

// ---- Phase 2d: coalesced gather of winner rows + index write ----
__global__ __launch_bounds__(256) void gather_kernel(
    const float* __restrict__ cb, const unsigned long long* __restrict__ best,
    float* __restrict__ zq, float* __restrict__ idx_out) {
  const int wave = threadIdx.x >> 6, lane = threadIdx.x & 63;
  const int row = blockIdx.x * 4 + wave;
  const int code = (int)(unsigned)(best[row] & 0xFFFFFFFFu);
  if (lane == 0) idx_out[row] = (float)code;
  const float4* cbv = (const float4*)(cb + (size_t)code * DIMS);
  float4* zqv = (float4*)(zq + (size_t)row * DIMS);
  zqv[lane]      = cbv[lane];
  zqv[lane + 64] = cbv[lane + 64];
}

extern "C" void kernel_launch(void* const* d_in, const int* in_sizes, int n_in,
                              void* d_out, int out_size, void* d_ws, size_t ws_size,
                              hipStream_t stream) {
  const float* z  = (const float*)d_in[0];
  const float* cb = (const float*)d_in[1];
  float* out     = (float*)d_out;
  float* zq      = out;
  float* idx_out = out + (size_t)N_ROWS * DIMS;

  // workspace layout (all chunks 256B-multiples)
  char* w = (char*)d_ws;
  _Float16* cbh = (_Float16*)w;            w += (size_t)KCODES * DIMS * 2;   // 8 MB
  float* zsq = (float*)w;                  w += (size_t)N_ROWS * 4;          // 128 KB
  float* csq = (float*)w;                  w += (size_t)KCODES * 4;          // 32 KB
  int* cnt_g = (int*)w;                    w += (size_t)NSEG * N_ROWS * 4;   // 512 KB
  unsigned* cand_g = (unsigned*)w;         w += (size_t)NSEG * N_ROWS * CAND * 4; // 16MB
  unsigned long long* best = (unsigned long long*)w; w += (size_t)N_ROWS * 8;  // 256 KB
  unsigned* pairs = (unsigned*)w;          w += (size_t)PAIR_CAP * 4;        // 1 MB
  int* meta = (int*)w;                     w += 256;                         // counters
  int* ovf = (int*)w;                      w += (size_t)N_ROWS * 4;          // 128 KB
  _Float16* zh = (_Float16*)w;             w += (size_t)N_ROWS * DIMS * 2;   // 32 MB
  bool use_zh = ((size_t)(w - (char*)d_ws) <= ws_size);

  hipMemsetAsync(meta, 0, 256, stream);

  rowsq_kernel<<<N_ROWS / 4, 256, 0, stream>>>(z, zsq);
  rowsq_kernel<<<KCODES / 4, 256, 0, stream>>>(cb, csq);
  cvt_cb_kernel<<<KCODES * DIMS / 1024, 256, 0, stream>>>(cb, cbh);
  if (use_zh) {
    cvt_z_kernel<<<N_ROWS * DIMS / 1024, 256, 0, stream>>>(z, zh);
    vq_mfma_kernel<true><<<(N_ROWS / 128) * NSEG, 512, 0, stream>>>(
        z, zh, cbh, csq, cand_g, cnt_g);
  } else {
    vq_mfma_kernel<false><<<(N_ROWS / 128) * NSEG, 512, 0, stream>>>(
        z, nullptr, cbh, csq, cand_g, cnt_g);
  }
  select_kernel<<<N_ROWS / 256, 256, 0, stream>>>(cnt_g, cand_g, best, pairs,
                                                  meta, ovf);
  pairs_kernel<<<PAIR_CAP / 256, 256, 0, stream>>>(z, cb, zsq, csq, pairs,
                                                   meta, best);
  fallback_kernel<<<512, 256, 0, stream>>>(z, cb, zsq, csq, ovf, meta, best);
  gather_kernel<<<N_ROWS / 4, 256, 0, stream>>>(cb, best, zq, idx_out);
}